// Round 1
// baseline (598.580 us; speedup 1.0000x reference)
//
#include <hip/hip_runtime.h>
#include <math.h>

#define IMG_W 384
#define IMG_H 384
#define IMG_HW (IMG_W * IMG_H)
#define N_IMG 512   /* B*C */
#define N_CH 64
#define N_B 8

// ---------------- Kernel 1: global average pool per (b,c) ----------------
__global__ __launch_bounds__(256) void pool_kernel(const float* __restrict__ x,
                                                   float* __restrict__ pooled) {
    const int bc = blockIdx.x;
    const float4* xp = (const float4*)(x + (size_t)bc * IMG_HW);
    const int t = threadIdx.x;
    float s = 0.f;
    // 147456 floats = 36864 float4 / 256 threads = 144 per thread, coalesced
    #pragma unroll 4
    for (int k = 0; k < 144; ++k) {
        float4 v = xp[t + k * 256];
        s += (v.x + v.y) + (v.z + v.w);
    }
    // wave64 reduction
    #pragma unroll
    for (int off = 32; off > 0; off >>= 1) s += __shfl_down(s, off, 64);
    __shared__ float red[4];
    if ((t & 63) == 0) red[t >> 6] = s;
    __syncthreads();
    if (t == 0) {
        float tot = (red[0] + red[1]) + (red[2] + red[3]);
        pooled[bc] = tot * (1.0f / (float)IMG_HW);
    }
}

// ---------------- Kernel 2: MLP -> separable normalized Gaussian taps ----
// guv layout: per sample b: [u0..u6, v0..v6]  (u = horizontal/cx, v = vertical/cy)
__global__ void params_kernel(const float* __restrict__ pooled,
                              const float* __restrict__ w1, const float* __restrict__ b1,
                              const float* __restrict__ w2, const float* __restrict__ b2,
                              float* __restrict__ guv) {
    const int b = threadIdx.x;
    if (b >= N_B) return;
    const float* P = pooled + b * N_CH;
    float h[16];
    #pragma unroll
    for (int j = 0; j < 16; ++j) {
        float acc = b1[j];
        for (int c = 0; c < N_CH; ++c) acc += P[c] * w1[j * N_CH + c];
        h[j] = acc / (1.f + expf(-acc));       // SiLU
    }
    float p[3];
    #pragma unroll
    for (int k = 0; k < 3; ++k) {
        float acc = b2[k];
        #pragma unroll
        for (int j = 0; j < 16; ++j) acc += h[j] * w2[k * 16 + j];
        p[k] = acc;
    }
    float sigma = (p[0] > 20.f) ? p[0] : log1pf(expf(p[0]));  // softplus
    float dx = tanhf(p[1]) * 2.f;
    float dy = tanhf(p[2]) * 2.f;
    float cx = 3.f + dx, cy = 3.f + dy;
    float inv2s2 = 1.f / (2.f * sigma * sigma);
    float u[7], v[7], su = 0.f, sv = 0.f;
    #pragma unroll
    for (int i = 0; i < 7; ++i) { float d = (float)i - cx; u[i] = expf(-d * d * inv2s2); su += u[i]; }
    #pragma unroll
    for (int j = 0; j < 7; ++j) { float d = (float)j - cy; v[j] = expf(-d * d * inv2s2); sv += v[j]; }
    float rsu = 1.f / su, rsv = 1.f / sv;
    #pragma unroll
    for (int i = 0; i < 7; ++i) guv[b * 14 + i] = u[i] * rsu;
    #pragma unroll
    for (int j = 0; j < 7; ++j) guv[b * 14 + 7 + j] = v[j] * rsv;
}

// ---------------- Kernel 3: separable 7x7 conv, streaming rows ------------
// One block per (b,c) image. 384 threads = one x-column each. Rows streamed
// in chunks of 8 through double-buffered LDS; rolling register window of
// horizontal-conv results (each input row's hconv computed exactly once).
// LDS row layout: [0..3]=zero pad, [4..387]=data cols 0..383, [388..391]=zero pad.
__global__ __launch_bounds__(384) void conv_kernel(const float* __restrict__ x,
                                                   const float* __restrict__ guv,
                                                   float* __restrict__ out) {
    __shared__ float buf[2][8][392];
    const int tid = threadIdx.x;
    const int bc = blockIdx.x;
    const int b = bc >> 6;                 // bc / N_CH
    const float* img = x + (size_t)bc * IMG_HW;
    float* oimg = out + (size_t)bc * IMG_HW;

    float u[7], v[7];
    #pragma unroll
    for (int i = 0; i < 7; ++i) { u[i] = guv[b * 14 + i]; v[i] = guv[b * 14 + 7 + i]; }

    // zero the pad columns of all 16 buffer rows (once)
    if (tid < 128) {
        int r = tid >> 3;                  // 0..15
        int p = tid & 7;                   // 0..7
        int col = (p < 4) ? p : (384 + p); // 0..3 or 388..391
        buf[r >> 3][r & 7][col] = 0.f;
    }

    // Prologue staging: rows -3..2 -> buf[1] rows 0..5 ; rows 3..10 -> buf[0]
    for (int q = tid; q < 576; q += 384) {          // 6 rows * 96 float4
        int brow = q / 96;
        int c4 = (q % 96) * 4;
        int row = -3 + brow;
        float4 val = make_float4(0.f, 0.f, 0.f, 0.f);
        if (row >= 0) val = *(const float4*)(img + row * IMG_W + c4);
        *(float4*)&buf[1][brow][4 + c4] = val;
    }
    #pragma unroll
    for (int k = 0; k < 2; ++k) {                   // 8 rows * 96 float4
        int q = tid + k * 384;
        int brow = q / 96;
        int c4 = (q % 96) * 4;
        float4 val = *(const float4*)(img + (3 + brow) * IMG_W + c4);
        *(float4*)&buf[0][brow][4 + c4] = val;
    }
    __syncthreads();

    // Prime rolling window: h[k] = hconv(input row k-3), k = 0..5
    const int xc = tid + 1;   // LDS col for data col (tid + i - 3) is tid + i + 1
    float h[6];
    #pragma unroll
    for (int k = 0; k < 6; ++k) {
        float a = 0.f;
        #pragma unroll
        for (int i = 0; i < 7; ++i) a += u[i] * buf[1][k][xc + i];
        h[k] = a;
    }

    // Main loop: 48 chunks of 8 output rows
    for (int c = 0; c < 48; ++c) {
        __syncthreads();
        // issue next chunk's loads into registers (rows 8(c+1)+3 .. +10)
        float4 nv[2];
        int brow_[2], c4_[2];
        const bool have_next = (c + 1 < 48);
        if (have_next) {
            int r0 = 8 * (c + 1) + 3;
            #pragma unroll
            for (int k = 0; k < 2; ++k) {
                int q = tid + k * 384;
                brow_[k] = q / 96;
                c4_[k] = (q % 96) * 4;
                int row = r0 + brow_[k];
                nv[k] = make_float4(0.f, 0.f, 0.f, 0.f);
                if (row < IMG_H) nv[k] = *(const float4*)(img + row * IMG_W + c4_[k]);
            }
        }
        // compute chunk c from buf[c&1] (input rows 8c+3 .. 8c+10)
        const float (*bufc)[392] = buf[c & 1];
        const int ybase = 8 * c;
        #pragma unroll
        for (int r = 0; r < 8; ++r) {
            float hn = 0.f;
            #pragma unroll
            for (int i = 0; i < 7; ++i) hn += u[i] * bufc[r][xc + i];
            float o = v[0] * h[0] + v[1] * h[1] + v[2] * h[2] + v[3] * h[3]
                    + v[4] * h[4] + v[5] * h[5] + v[6] * hn;
            oimg[(ybase + r) * IMG_W + tid] = o;
            #pragma unroll
            for (int k = 0; k < 5; ++k) h[k] = h[k + 1];
            h[5] = hn;
        }
        // write staged registers into the alternate buffer (after compute)
        if (have_next) {
            float (*bufn)[392] = buf[(c + 1) & 1];
            #pragma unroll
            for (int k = 0; k < 2; ++k) {
                *(float4*)&bufn[brow_[k]][4 + c4_[k]] = nv[k];
            }
        }
    }
}

extern "C" void kernel_launch(void* const* d_in, const int* in_sizes, int n_in,
                              void* d_out, int out_size, void* d_ws, size_t ws_size,
                              hipStream_t stream) {
    const float* x  = (const float*)d_in[0];
    const float* w1 = (const float*)d_in[1];
    const float* b1 = (const float*)d_in[2];
    const float* w2 = (const float*)d_in[3];
    const float* b2 = (const float*)d_in[4];
    float* outp = (float*)d_out;

    float* pooled = (float*)d_ws;          // 512 floats
    float* guv    = pooled + 512;          // 112 floats

    pool_kernel<<<N_IMG, 256, 0, stream>>>(x, pooled);
    params_kernel<<<1, 64, 0, stream>>>(pooled, w1, b1, w2, b2, guv);
    conv_kernel<<<N_IMG, 384, 0, stream>>>(x, guv, outp);
}